// Round 5
// baseline (387.571 us; speedup 1.0000x reference)
//
#include <hip/hip_runtime.h>
#include <stdint.h>

#define N_NODES 100000
#define N_EDGES 1250000
#define D_FEAT 64
#define DROP_SIZE 875000   // int(0.7*E): 0.7*1250000 rounds to exactly 875000.0

// ---------------- Threefry-2x32 core (verified vs Random123 KAT) ----------------
struct TF { uint32_t a, b; };

__host__ __device__ constexpr TF tf2x32(uint32_t k0, uint32_t k1, uint32_t x0, uint32_t x1) {
  uint32_t ks[3] = {k0, k1, k0 ^ k1 ^ 0x1BD11BDAu};
  const int rot[8] = {13, 15, 26, 6, 17, 29, 16, 24};
  x0 += ks[0]; x1 += ks[1];
  for (int g = 0; g < 5; ++g) {
    for (int j = 0; j < 4; ++j) {
      int r = rot[(g & 1) * 4 + j];
      x0 += x1;
      x1 = (x1 << r) | (x1 >> (32 - r));
      x1 ^= x0;
    }
    x0 += ks[(g + 1) % 3];
    x1 += ks[(g + 2) % 3] + (uint32_t)(g + 1);
  }
  return TF{x0, x1};
}

// R4 HYPOTHESIS (untested — R4 bench timed out; resubmitting unchanged):
// env jax has jax_threefry_partitionable=True (default since jax 0.5).
//   key(0) = [0,0]
//   fold_in(key,1) = threefry(key, threefry_seed(1)=[0,1])        (no partitionable variant)
//   split(KEYA,2) foldlike: key_j = full output of block (0, j)   -> k2 = tf(KEYA, 0, 1)
//   random_bits(k2, 32, (n,)) partitionable: elem i = y0^y1 of block (0, i)
//   randint: multiplier = ((2^16 % span)^2 mod 2^32) % span == 0  -> ridx = bits % span
constexpr TF KEYA = tf2x32(0u, 0u, 0u, 1u);
constexpr TF K2   = tf2x32(KEYA.a, KEYA.b, 0u, 1u);   // split row 1 (lower_bits key)

// ---------------- workspace layout (bytes) ----------------
#define OFF_DROPPED 0u                 // E bytes (padded to 1250048)
#define OFF_DEGOUT  1250048u           // N int
#define OFF_DEGIN   1650048u           // N int
#define OFF_CNT     2050048u           // N int (kept in-degree)
#define OFF_FILL    2450048u           // N int
#define OFF_CURSOR  2850048u           // 1 int (+pad)
#define ZERO_BYTES  2850112u           // everything above is zero-initialized
#define OFF_START   2850112u           // N int
#define OFF_NOUT    3250112u           // N float
#define OFF_NIN     3650112u           // N float
#define OFF_SRCS    4050112u           // E int   (compacted CSR col indices)
#define OFF_WV      9050112u           // E float (compacted CSR weights)
#define OFF_H1      14050112u          // N*64 float
#define WS_NEEDED   39650112u

// ---------------- kernels ----------------
__global__ __launch_bounds__(256) void k_drop(unsigned char* dropped) {
  int i = blockIdx.x * 256 + threadIdx.x;
  if (i >= DROP_SIZE) return;
  TF r = tf2x32(K2.a, K2.b, 0u, (uint32_t)i);   // 64b counter i: hi=0 -> x0, lo=i -> x1
  uint32_t bits = r.a ^ r.b;                     // partitionable 32-bit collapse
  dropped[bits % (uint32_t)N_EDGES] = 1;
}

__global__ __launch_bounds__(256) void k_edges(const int* __restrict__ src,
                                               const int* __restrict__ dst,
                                               const float* __restrict__ ew,
                                               const unsigned char* __restrict__ dropped,
                                               int* deg_out, int* deg_in, int* cnt) {
  int e = blockIdx.x * 256 + threadIdx.x;
  if (e >= N_EDGES) return;
  int s = src[e], d = dst[e];
  atomicAdd(&deg_out[s], 1);
  atomicAdd(&deg_in[d], 1);
  if (!dropped[e] && ew[e] != 0.0f) atomicAdd(&cnt[d], 1);
}

__global__ __launch_bounds__(256) void k_alloc(const int* __restrict__ cnt,
                                               const int* __restrict__ deg_out,
                                               const int* __restrict__ deg_in,
                                               int* start, float* nout, float* nin, int* cursor) {
  int n = blockIdx.x * 256 + threadIdx.x;
  int lane = threadIdx.x & 63;
  bool valid = n < N_NODES;
  int c = valid ? cnt[n] : 0;
  int x = c;                      // wave-inclusive scan
  #pragma unroll
  for (int off = 1; off < 64; off <<= 1) {
    int y = __shfl_up(x, off);
    if (lane >= off) x += y;
  }
  int excl = x - c;
  int total = __shfl(x, 63);
  int base = 0;
  if (lane == 0) base = atomicAdd(cursor, total);
  base = __shfl(base, 0);
  if (valid) {
    start[n] = base + excl;
    nout[n] = 1.0f / sqrtf((float)(deg_out[n] > 1 ? deg_out[n] : 1));
    nin[n]  = 1.0f / sqrtf((float)(deg_in[n]  > 1 ? deg_in[n]  : 1));
  }
}

__global__ __launch_bounds__(256) void k_scatter(const int* __restrict__ src,
                                                 const int* __restrict__ dst,
                                                 const float* __restrict__ ew,
                                                 const unsigned char* __restrict__ dropped,
                                                 const int* __restrict__ start,
                                                 int* fill, int* srcs, float* wv) {
  int e = blockIdx.x * 256 + threadIdx.x;
  if (e >= N_EDGES) return;
  float w = ew[e];
  if (dropped[e] || w == 0.0f) return;  // zero-weight edges contribute exactly 0
  int d = dst[e];
  int p = start[d] + atomicAdd(&fill[d], 1);
  srcs[p] = src[e];
  wv[p] = w;
}

// wave-per-node gather conv. gin is the UN-prescaled layer input; the
// reference's h*norm_out pre-scale is applied per-edge as gin[s]*nout[s].
template <bool FINAL>
__global__ __launch_bounds__(256) void k_conv(const int* __restrict__ srcs,
                                              const float* __restrict__ wv,
                                              const int* __restrict__ start,
                                              const int* __restrict__ cnt,
                                              const float* __restrict__ nin,
                                              const float* __restrict__ nout,
                                              const float* __restrict__ gin,
                                              const float* __restrict__ feat,
                                              float* __restrict__ out0) {
  int w = (blockIdx.x * blockDim.x + threadIdx.x) >> 6;
  int lane = threadIdx.x & 63;
  if (w >= N_NODES) return;
  int s0 = start[w], c = cnt[w];
  float acc = 0.0f;
  for (int base = 0; base < c; base += 64) {
    int kk = base + lane;
    bool in = kk < c;
    int   sv = in ? srcs[s0 + kk] : 0;        // coalesced: one edge per lane
    float wt = in ? wv[s0 + kk] : 0.0f;
    float ns = in ? nout[sv] : 0.0f;          // prefetch src-node norm
    int lim = (c - base) < 64 ? (c - base) : 64;
    for (int k = 0; k < lim; ++k) {
      int   s  = __shfl(sv, k);
      float wk = __shfl(wt, k);
      float nk = __shfl(ns, k);
      float g = gin[s * D_FEAT + lane] * nk;  // == reference's prescaled row
      acc = fmaf(wk, g, acc);
    }
  }
  float h = acc * nin[w];
  int idx = w * D_FEAT + lane;
  if (FINAL) {
    out0[idx] = (feat[idx] + gin[idx] + h) / 3.0f;  // (f + h1 + h2)/3
  } else {
    out0[idx] = h;
  }
}

// ---------------- launch ----------------
extern "C" void kernel_launch(void* const* d_in, const int* in_sizes, int n_in,
                              void* d_out, int out_size, void* d_ws, size_t ws_size,
                              hipStream_t stream) {
  if (ws_size < (size_t)WS_NEEDED) return;  // output stays zero -> loud failure

  const float* feature = (const float*)d_in[0];
  const float* edge_w  = (const float*)d_in[1];
  const int*   src     = (const int*)d_in[2];
  const int*   dst     = (const int*)d_in[3];
  float* out = (float*)d_out;

  char* ws = (char*)d_ws;
  unsigned char* dropped = (unsigned char*)(ws + OFF_DROPPED);
  int*   deg_out = (int*)(ws + OFF_DEGOUT);
  int*   deg_in  = (int*)(ws + OFF_DEGIN);
  int*   cnt     = (int*)(ws + OFF_CNT);
  int*   fill    = (int*)(ws + OFF_FILL);
  int*   cursor  = (int*)(ws + OFF_CURSOR);
  int*   startp  = (int*)(ws + OFF_START);
  float* nout    = (float*)(ws + OFF_NOUT);
  float* nin     = (float*)(ws + OFF_NIN);
  int*   srcs    = (int*)(ws + OFF_SRCS);
  float* wv      = (float*)(ws + OFF_WV);
  float* h1      = (float*)(ws + OFF_H1);

  hipMemsetAsync(ws, 0, ZERO_BYTES, stream);

  k_drop<<<(DROP_SIZE + 255) / 256, 256, 0, stream>>>(dropped);
  k_edges<<<(N_EDGES + 255) / 256, 256, 0, stream>>>(src, dst, edge_w, dropped,
                                                     deg_out, deg_in, cnt);
  k_alloc<<<(N_NODES + 255) / 256, 256, 0, stream>>>(cnt, deg_out, deg_in,
                                                     startp, nout, nin, cursor);
  k_scatter<<<(N_EDGES + 255) / 256, 256, 0, stream>>>(src, dst, edge_w, dropped,
                                                       startp, fill, srcs, wv);
  // layer 1: h1 = nin * sum(w * feat[src]*nout[src])
  k_conv<false><<<(N_NODES * D_FEAT + 255) / 256, 256, 0, stream>>>(
      srcs, wv, startp, cnt, nin, nout, feature, nullptr, h1);
  // layer 2 + fused mix: out = (feature + h1 + h2) / 3
  k_conv<true><<<(N_NODES * D_FEAT + 255) / 256, 256, 0, stream>>>(
      srcs, wv, startp, cnt, nin, nout, h1, feature, out);
}

// Round 6
// 311.207 us; speedup vs baseline: 1.2454x; 1.2454x over previous
//
#include <hip/hip_runtime.h>
#include <stdint.h>

#define N_NODES 100000
#define N_EDGES 1250000
#define D_FEAT 64
#define DROP_SIZE 875000   // int(0.7*E)
#define CAP 64             // per-node kept-in-degree capacity (Poisson(6.2); P(>63)<1e-12)

// ---------------- Threefry-2x32 core (verified vs Random123 KAT) ----------------
struct TF { uint32_t a, b; };

__host__ __device__ constexpr TF tf2x32(uint32_t k0, uint32_t k1, uint32_t x0, uint32_t x1) {
  uint32_t ks[3] = {k0, k1, k0 ^ k1 ^ 0x1BD11BDAu};
  const int rot[8] = {13, 15, 26, 6, 17, 29, 16, 24};
  x0 += ks[0]; x1 += ks[1];
  for (int g = 0; g < 5; ++g) {
    for (int j = 0; j < 4; ++j) {
      int r = rot[(g & 1) * 4 + j];
      x0 += x1;
      x1 = (x1 << r) | (x1 >> (32 - r));
      x1 ^= x0;
    }
    x0 += ks[(g + 1) % 3];
    x1 += ks[(g + 2) % 3] + (uint32_t)(g + 1);
  }
  return TF{x0, x1};
}

// VERIFIED (R5 pass): jax_threefry_partitionable scheme.
//   KEYA = fold_in(key(0),1) = tf([0,0],(0,1)); K2 = split row 1 = tf(KEYA,(0,1))
//   bits_i = y0^y1 of tf(K2,(0,i)); ridx = bits % E (randint multiplier wraps to 0)
constexpr TF KEYA = tf2x32(0u, 0u, 0u, 1u);
constexpr TF K2   = tf2x32(KEYA.a, KEYA.b, 0u, 1u);

// ---------------- workspace layout (bytes); ws_size >= 90.85 MB (proven R2) ----
#define OFF_DROPPED 0u                 // E bytes (padded to 1250048)
#define OFF_PACKED  1250048u           // N u32: deg_in (lo16) | kept_cnt (hi16)
#define OFF_DEGOUT  1650048u           // N int
#define ZERO_BYTES  2050048u           // everything above zero-initialized
#define OFF_NOUT    2050048u           // N float
#define OFF_NIN     2450048u           // N float
#define OFF_PAIRS   2850048u           // N*CAP int2 {src, w_bits} = 51.2 MB
#define OFF_H1      54050048u          // N*64 float
#define WS_NEEDED   79650048u

// ---------------- kernels ----------------
__global__ __launch_bounds__(256) void k_drop(unsigned char* dropped) {
  int i = blockIdx.x * 256 + threadIdx.x;
  if (i >= DROP_SIZE) return;
  TF r = tf2x32(K2.a, K2.b, 0u, (uint32_t)i);
  uint32_t bits = r.a ^ r.b;
  dropped[bits % (uint32_t)N_EDGES] = 1;
}

// fused degree-count + slot-alloc + CSR scatter: 2 device atomics per edge
__global__ __launch_bounds__(256) void k_build(const int* __restrict__ src,
                                               const int* __restrict__ dst,
                                               const float* __restrict__ ew,
                                               const unsigned char* __restrict__ dropped,
                                               int* deg_out, unsigned* packed,
                                               int2* __restrict__ pairs) {
  int e = blockIdx.x * 256 + threadIdx.x;
  if (e >= N_EDGES) return;
  int s = src[e], d = dst[e];
  atomicAdd(&deg_out[s], 1);
  float w = ew[e];
  bool kept = (!dropped[e]) && (w != 0.0f);   // zero-weight edges contribute exactly 0
  unsigned add = 1u + (kept ? (1u << 16) : 0u);
  unsigned old = atomicAdd(&packed[d], add);  // lo16: deg_in, hi16: kept slot alloc
  if (kept) {
    unsigned slot = old >> 16;                // < CAP for this fixed graph
    pairs[(unsigned)d * CAP + slot] = make_int2(s, __float_as_int(w));
  }
}

__global__ __launch_bounds__(256) void k_norm(const unsigned* __restrict__ packed,
                                              const int* __restrict__ deg_out,
                                              float* nout, float* nin) {
  int n = blockIdx.x * 256 + threadIdx.x;
  if (n >= N_NODES) return;
  int din = (int)(packed[n] & 0xFFFFu);
  int dou = deg_out[n];
  nin[n]  = 1.0f / sqrtf((float)(din > 1 ? din : 1));
  nout[n] = 1.0f / sqrtf((float)(dou > 1 ? dou : 1));
}

// wave-per-node gather conv; per-node edge list fits one 64-lane load (CAP=64).
// pre-scale applied per-edge as gin[s]*nout[s] (same arithmetic as R5-passing version).
template <bool FINAL>
__global__ __launch_bounds__(256) void k_conv(const int2* __restrict__ pairs,
                                              const unsigned* __restrict__ packed,
                                              const float* __restrict__ nin,
                                              const float* __restrict__ nout,
                                              const float* __restrict__ gin,
                                              const float* __restrict__ feat,
                                              float* __restrict__ out0) {
  int w = (blockIdx.x * blockDim.x + threadIdx.x) >> 6;
  int lane = threadIdx.x & 63;
  if (w >= N_NODES) return;
  int c = (int)(packed[w] >> 16);
  int2 pr = make_int2(0, 0);
  float ns = 0.0f;
  if (lane < c) {
    pr = pairs[(unsigned)w * CAP + lane];     // coalesced: one edge per lane
    ns = nout[pr.x];                          // prefetch src-node norm
  }
  float wt = __int_as_float(pr.y);
  float acc = 0.0f;
  for (int k = 0; k < c; ++k) {
    int   s  = __shfl(pr.x, k);
    float wk = __shfl(wt, k);
    float nk = __shfl(ns, k);
    float g = gin[s * D_FEAT + lane] * nk;    // == reference's prescaled row
    acc = fmaf(wk, g, acc);
  }
  float h = acc * nin[w];
  int idx = w * D_FEAT + lane;
  if (FINAL) {
    out0[idx] = (feat[idx] + gin[idx] + h) / 3.0f;  // (f + h1 + h2)/3
  } else {
    out0[idx] = h;
  }
}

// ---------------- launch ----------------
extern "C" void kernel_launch(void* const* d_in, const int* in_sizes, int n_in,
                              void* d_out, int out_size, void* d_ws, size_t ws_size,
                              hipStream_t stream) {
  if (ws_size < (size_t)WS_NEEDED) return;  // output stays zero -> loud failure

  const float* feature = (const float*)d_in[0];
  const float* edge_w  = (const float*)d_in[1];
  const int*   src     = (const int*)d_in[2];
  const int*   dst     = (const int*)d_in[3];
  float* out = (float*)d_out;

  char* ws = (char*)d_ws;
  unsigned char* dropped = (unsigned char*)(ws + OFF_DROPPED);
  unsigned* packed = (unsigned*)(ws + OFF_PACKED);
  int*      deg_out = (int*)(ws + OFF_DEGOUT);
  float*    nout = (float*)(ws + OFF_NOUT);
  float*    nin  = (float*)(ws + OFF_NIN);
  int2*     pairs = (int2*)(ws + OFF_PAIRS);
  float*    h1   = (float*)(ws + OFF_H1);

  hipMemsetAsync(ws, 0, ZERO_BYTES, stream);

  k_drop<<<(DROP_SIZE + 255) / 256, 256, 0, stream>>>(dropped);
  k_build<<<(N_EDGES + 255) / 256, 256, 0, stream>>>(src, dst, edge_w, dropped,
                                                     deg_out, packed, pairs);
  k_norm<<<(N_NODES + 255) / 256, 256, 0, stream>>>(packed, deg_out, nout, nin);
  // layer 1: h1 = nin * sum(w * feat[src]*nout[src])
  k_conv<false><<<(N_NODES * D_FEAT + 255) / 256, 256, 0, stream>>>(
      pairs, packed, nin, nout, feature, nullptr, h1);
  // layer 2 + fused mix: out = (feature + h1 + h2) / 3
  k_conv<true><<<(N_NODES * D_FEAT + 255) / 256, 256, 0, stream>>>(
      pairs, packed, nin, nout, h1, feature, out);
}

// Round 7
// 279.843 us; speedup vs baseline: 1.3850x; 1.1121x over previous
//
#include <hip/hip_runtime.h>
#include <stdint.h>

#define N_NODES 100000
#define N_EDGES 1250000
#define D_FEAT 64
#define DROP_SIZE 875000   // int(0.7*E)
#define CAP 64             // per-node kept-in-degree capacity (Poisson(6.2); P(>63)<1e-12)

// ---------------- Threefry-2x32 core (verified vs Random123 KAT) ----------------
struct TF { uint32_t a, b; };

__host__ __device__ constexpr TF tf2x32(uint32_t k0, uint32_t k1, uint32_t x0, uint32_t x1) {
  uint32_t ks[3] = {k0, k1, k0 ^ k1 ^ 0x1BD11BDAu};
  const int rot[8] = {13, 15, 26, 6, 17, 29, 16, 24};
  x0 += ks[0]; x1 += ks[1];
  for (int g = 0; g < 5; ++g) {
    for (int j = 0; j < 4; ++j) {
      int r = rot[(g & 1) * 4 + j];
      x0 += x1;
      x1 = (x1 << r) | (x1 >> (32 - r));
      x1 ^= x0;
    }
    x0 += ks[(g + 1) % 3];
    x1 += ks[(g + 2) % 3] + (uint32_t)(g + 1);
  }
  return TF{x0, x1};
}

// VERIFIED (R5/R6 pass): jax_threefry_partitionable scheme.
constexpr TF KEYA = tf2x32(0u, 0u, 0u, 1u);
constexpr TF K2   = tf2x32(KEYA.a, KEYA.b, 0u, 1u);

// ---------------- workspace layout (bytes); ws_size >= 90.85 MB (proven R2) ----
#define OFF_DROPPED 0u                 // E bytes (padded to 1250048)
#define OFF_PACKED  1250048u           // N u32: deg_in (lo16) | kept_cnt (hi16)
#define OFF_DEGOUT  1650048u           // N int
#define ZERO_BYTES  2050048u           // everything above zero-initialized
#define OFF_NOUT    2050048u           // N float
#define OFF_NIN     2450048u           // N float
#define OFF_PAIRS   2850048u           // N*CAP int2 {src, w_bits} = 51.2 MB
#define OFF_H1      54050048u          // N*64 float
#define WS_NEEDED   79650048u

// ---------------- kernels ----------------
__global__ __launch_bounds__(256) void k_drop(unsigned char* dropped) {
  int i = blockIdx.x * 256 + threadIdx.x;
  if (i >= DROP_SIZE) return;
  TF r = tf2x32(K2.a, K2.b, 0u, (uint32_t)i);
  uint32_t bits = r.a ^ r.b;
  dropped[bits % (uint32_t)N_EDGES] = 1;
}

// fused degree-count + slot-alloc + CSR scatter: 2 device atomics per edge
// (R6 evidence: bound by memory-side atomic write-through, not issue count)
__global__ __launch_bounds__(256) void k_build(const int* __restrict__ src,
                                               const int* __restrict__ dst,
                                               const float* __restrict__ ew,
                                               const unsigned char* __restrict__ dropped,
                                               int* deg_out, unsigned* packed,
                                               int2* __restrict__ pairs) {
  int e = blockIdx.x * 256 + threadIdx.x;
  if (e >= N_EDGES) return;
  int s = src[e], d = dst[e];
  atomicAdd(&deg_out[s], 1);
  float w = ew[e];
  bool kept = (!dropped[e]) && (w != 0.0f);   // zero-weight edges contribute exactly 0
  unsigned add = 1u + (kept ? (1u << 16) : 0u);
  unsigned old = atomicAdd(&packed[d], add);  // lo16: deg_in, hi16: kept slot alloc
  if (kept) {
    unsigned slot = old >> 16;                // < CAP for this fixed graph
    pairs[(unsigned)d * CAP + slot] = make_int2(s, __float_as_int(w));
  }
}

__global__ __launch_bounds__(256) void k_norm(const unsigned* __restrict__ packed,
                                              const int* __restrict__ deg_out,
                                              float* nout, float* nin) {
  int n = blockIdx.x * 256 + threadIdx.x;
  if (n >= N_NODES) return;
  int din = (int)(packed[n] & 0xFFFFu);
  int dou = deg_out[n];
  nin[n]  = 1.0f / sqrtf((float)(din > 1 ? din : 1));
  nout[n] = 1.0f / sqrtf((float)(dou > 1 ? dou : 1));
}

// wave-per-node gather conv, unrolled x4 for memory-level parallelism.
// Lanes >= c hold {s=0, coef=0} so padded iterations read row 0 and add 0.
template <bool FINAL>
__global__ __launch_bounds__(256) void k_conv(const int2* __restrict__ pairs,
                                              const unsigned* __restrict__ packed,
                                              const float* __restrict__ nin,
                                              const float* __restrict__ nout,
                                              const float* __restrict__ gin,
                                              const float* __restrict__ feat,
                                              float* __restrict__ out0) {
  int w = (blockIdx.x * blockDim.x + threadIdx.x) >> 6;
  int lane = threadIdx.x & 63;
  if (w >= N_NODES) return;
  int c = (int)(packed[w] >> 16);
  int2 pr = make_int2(0, 0);
  float ns = 0.0f;
  if (lane < c) {
    pr = pairs[(unsigned)w * CAP + lane];     // coalesced: one edge per lane
    ns = nout[pr.x];                          // src-node norm gather
  }
  float coef = __int_as_float(pr.y) * ns;     // w * nout[s]; exactly 0 for lane>=c
  float nw = nin[w];
  float acc = 0.0f;
  int c4 = (c + 3) & ~3;
  for (int k = 0; k < c4; k += 4) {
    int   s0 = __shfl(pr.x, k);     float f0 = __shfl(coef, k);
    int   s1 = __shfl(pr.x, k + 1); float f1 = __shfl(coef, k + 1);
    int   s2 = __shfl(pr.x, k + 2); float f2 = __shfl(coef, k + 2);
    int   s3 = __shfl(pr.x, k + 3); float f3 = __shfl(coef, k + 3);
    float g0 = gin[s0 * D_FEAT + lane];       // 4 independent 256B row gathers
    float g1 = gin[s1 * D_FEAT + lane];
    float g2 = gin[s2 * D_FEAT + lane];
    float g3 = gin[s3 * D_FEAT + lane];
    acc = fmaf(f0, g0, acc);
    acc = fmaf(f1, g1, acc);
    acc = fmaf(f2, g2, acc);
    acc = fmaf(f3, g3, acc);
  }
  float h = acc * nw;
  int idx = w * D_FEAT + lane;
  if (FINAL) {
    out0[idx] = (feat[idx] + gin[idx] + h) / 3.0f;  // (f + h1 + h2)/3
  } else {
    out0[idx] = h;
  }
}

// ---------------- launch ----------------
extern "C" void kernel_launch(void* const* d_in, const int* in_sizes, int n_in,
                              void* d_out, int out_size, void* d_ws, size_t ws_size,
                              hipStream_t stream) {
  if (ws_size < (size_t)WS_NEEDED) return;  // output stays zero -> loud failure

  const float* feature = (const float*)d_in[0];
  const float* edge_w  = (const float*)d_in[1];
  const int*   src     = (const int*)d_in[2];
  const int*   dst     = (const int*)d_in[3];
  float* out = (float*)d_out;

  char* ws = (char*)d_ws;
  unsigned char* dropped = (unsigned char*)(ws + OFF_DROPPED);
  unsigned* packed = (unsigned*)(ws + OFF_PACKED);
  int*      deg_out = (int*)(ws + OFF_DEGOUT);
  float*    nout = (float*)(ws + OFF_NOUT);
  float*    nin  = (float*)(ws + OFF_NIN);
  int2*     pairs = (int2*)(ws + OFF_PAIRS);
  float*    h1   = (float*)(ws + OFF_H1);

  hipMemsetAsync(ws, 0, ZERO_BYTES, stream);

  k_drop<<<(DROP_SIZE + 255) / 256, 256, 0, stream>>>(dropped);
  k_build<<<(N_EDGES + 255) / 256, 256, 0, stream>>>(src, dst, edge_w, dropped,
                                                     deg_out, packed, pairs);
  k_norm<<<(N_NODES + 255) / 256, 256, 0, stream>>>(packed, deg_out, nout, nin);
  // layer 1: h1 = nin * sum(w*nout[s] * feat[s])
  k_conv<false><<<(N_NODES * D_FEAT + 255) / 256, 256, 0, stream>>>(
      pairs, packed, nin, nout, feature, nullptr, h1);
  // layer 2 + fused mix: out = (feature + h1 + h2) / 3
  k_conv<true><<<(N_NODES * D_FEAT + 255) / 256, 256, 0, stream>>>(
      pairs, packed, nin, nout, h1, feature, out);
}